// Round 9
// baseline (4190.409 us; speedup 1.0000x reference)
//
#include <hip/hip_runtime.h>

// SimpleLSTM: 2-layer LSTM (B=512,T=256,F=64,U=128) + Dense(1,relu).
// R9: FUSED LAYER PIPELINE. 4 batch rows/WG packed into the SAME 128 h@U
// MFMAs (A-rows 0,4,8,12 -> C reg0 of the four 16-lane groups) => each layer
// needs only 128 WGs; both layers run concurrently on disjoint CU halves.
// Layer2 (blocks 128..255) trails layer1 (blocks 0..127) by ~3 4-step blocks,
// synced by per-block device-scope flags (release-agent after producer's
// block stores, acquire-agent before consumer's block loads). Producers never
// wait => no deadlock; waves_per_eu(2,2) => 1 WG/CU, all 256 co-resident.
// Worst case (no co-residency): degenerates to sequential execution, still
// correct. Epilogue now runs on all 64 lanes (4 c-chains).

#define T_STEPS 256
#define BATCH   512
#define NU      128
#define FDIM    64
#define NB      64            // 4-step blocks
#define FLAGV   0x0C0DE000

typedef _Float16 h8 __attribute__((ext_vector_type(8)));
typedef _Float16 h4 __attribute__((ext_vector_type(4)));
typedef float    f4 __attribute__((ext_vector_type(4)));

#define LOG2E    1.4426950408889634f
#define TWOLOG2E 2.8853900817779268f

// LDS-only barrier (no vmcnt drain) for non-flag steps.
#define WG_BARRIER() asm volatile("s_waitcnt lgkmcnt(0)\n\ts_barrier" ::: "memory")

#if __has_builtin(__builtin_amdgcn_exp2f)
#define EXP2F(x) __builtin_amdgcn_exp2f(x)
#else
#define EXP2F(x) exp2f(x)
#endif
#if __has_builtin(__builtin_amdgcn_rcpf)
#define RCPF(x) __builtin_amdgcn_rcpf(x)
#else
#define RCPF(x) (1.0f / (x))
#endif

__device__ __forceinline__ float sigm2(float s) {   // s = -z*log2e
    return RCPF(1.0f + EXP2F(s));
}
__device__ __forceinline__ float tanh2(float t) {   // t = 2*z*log2e
    return 1.0f - 2.0f * RCPF(1.0f + EXP2F(t));
}

// ---- weight prep: col-major [col][k], fp16, gate-folded log2e signs ----
__global__ void prep_weights(const float* __restrict__ W1, const float* __restrict__ U1,
                             const float* __restrict__ b1, const float* __restrict__ W2,
                             const float* __restrict__ U2, const float* __restrict__ b2,
                             _Float16* __restrict__ Wp1, _Float16* __restrict__ Up1,
                             _Float16* __restrict__ Wp2, _Float16* __restrict__ Up2,
                             float* __restrict__ bp1, float* __restrict__ bp2) {
    int i = blockIdx.x * 256 + threadIdx.x;
    if (i < 32768) {
        int col = i >> 6, k = i & 63;
        float sc = ((col >> 7) == 2) ? TWOLOG2E : -LOG2E;
        Wp1[i] = (_Float16)(W1[k * 512 + col] * sc);
    } else if (i < 98304) {
        int j = i - 32768; int col = j >> 7, k = j & 127;
        float sc = ((col >> 7) == 2) ? TWOLOG2E : -LOG2E;
        Up1[j] = (_Float16)(U1[k * 512 + col] * sc);
    } else if (i < 163840) {
        int j = i - 98304; int col = j >> 7, k = j & 127;
        float sc = ((col >> 7) == 2) ? TWOLOG2E : -LOG2E;
        Wp2[j] = (_Float16)(W2[k * 512 + col] * sc);
    } else if (i < 229376) {
        int j = i - 163840; int col = j >> 7, k = j & 127;
        float sc = ((col >> 7) == 2) ? TWOLOG2E : -LOG2E;
        Up2[j] = (_Float16)(U2[k * 512 + col] * sc);
    } else if (i < 230400) {
        int j = i - 229376;
        if (j < 512) {
            float sc = ((j >> 7) == 2) ? TWOLOG2E : -LOG2E;
            bp1[j] = b1[j] * sc;
        } else {
            int col = j - 512;
            float sc = ((col >> 7) == 2) ? TWOLOG2E : -LOG2E;
            bp2[col] = b2[col] * sc;
        }
    }
}

// ---- per-layer body (IS_A: producer/layer1; else consumer/layer2+dense) ----
template <bool IS_A>
__device__ __forceinline__ void lstm_body(
    _Float16* smh, float* smxz,
    const float* __restrict__ xA, const _Float16* __restrict__ xB,
    const _Float16* __restrict__ Wp, const _Float16* __restrict__ Up,
    const float* __restrict__ bp, _Float16* __restrict__ hs,
    const float* __restrict__ Wd, const float* __restrict__ bd,
    float* __restrict__ dout, int* flags, int wg) {
    constexpr int KX  = IS_A ? 64 : 128;
    constexpr int KXS = KX / 32;
    constexpr int PH  = 136;

    const int tid  = threadIdx.x;
    const int lane = tid & 63;
    const int wv   = tid >> 6;
    const int m    = lane & 15;
    const int kc   = lane >> 4;
    const int u0   = wv * 16;
    const int b0   = wg * 4;
    const int erow = lane >> 4;      // 0..3: batch row owned in epilogue

    // zero both h buffers (h0 = 0)
    for (int i = tid; i < 8 * PH; i += 512) smh[i] = (_Float16)0.0f;

    // B-frags: B[k=kc*8+j][n=col]
    h8 uf[4][4];
#pragma unroll
    for (int g = 0; g < 4; g++)
#pragma unroll
        for (int ks = 0; ks < 4; ks++)
            uf[g][ks] = *(const h8*)&Up[(g * 128 + u0 + m) * 128 + ks * 32 + kc * 8];
    h8 wf[4][KXS];
#pragma unroll
    for (int g = 0; g < 4; g++)
#pragma unroll
        for (int ks = 0; ks < KXS; ks++)
            wf[g][ks] = *(const h8*)&Wp[(g * 128 + u0 + m) * KX + ks * 32 + kc * 8];
    float bias[4];
#pragma unroll
    for (int g = 0; g < 4; g++) bias[g] = bp[g * 128 + u0 + m];

    // A-frags for x-projection: lane m supplies A-row m = (step m>>2, brow m&3)
    f4 rX[2][2 * KXS];
    h8 rH[2][4];
    auto loadA = [&](int blk, int buf) {
        int tt = blk * 4 + (m >> 2); if (tt > T_STEPS - 1) tt = T_STEPS - 1;
        const int bb = b0 + (m & 3);
        if constexpr (IS_A) {
#pragma unroll
            for (int ks = 0; ks < KXS; ks++)
#pragma unroll
                for (int hf = 0; hf < 2; hf++)
                    rX[buf][ks * 2 + hf] = *(const f4*)&xA[((size_t)bb * T_STEPS + tt) * FDIM
                                                           + ks * 32 + kc * 8 + hf * 4];
        } else {
#pragma unroll
            for (int ks = 0; ks < 4; ks++)
                rH[buf][ks] = *(const h8*)&xB[((size_t)tt * BATCH + bb) * NU + ks * 32 + kc * 8];
        }
    };

    auto waitflag = [&](int idx) {   // consumer only; wave0 polls, barrier gates rest
        if (wv == 0) {
            const int want = FLAGV + idx;
            while (__hip_atomic_load(&flags[wg * NB + idx], __ATOMIC_RELAXED,
                                     __HIP_MEMORY_SCOPE_AGENT) != want)
                __builtin_amdgcn_s_sleep(8);
            __builtin_amdgcn_fence(__ATOMIC_ACQUIRE, "agent");
        }
    };

    f4 accx[4];
    h8 aX[IS_A ? KXS : 1];
    auto accxInit = [&] {
#pragma unroll
        for (int g = 0; g < 4; g++) accx[g] = (f4){bias[g], bias[g], bias[g], bias[g]};
    };
    auto cvtA = [&](int buf) {
        if constexpr (IS_A) {
#pragma unroll
            for (int ks = 0; ks < KXS; ks++) {
                f4 lo = rX[buf][2 * ks], hi = rX[buf][2 * ks + 1];
                h8 a;
#pragma unroll
                for (int j = 0; j < 4; j++) { a[j] = (_Float16)lo[j]; a[4 + j] = (_Float16)hi[j]; }
                aX[ks] = a;
            }
        }
    };
    auto xPiece = [&](int buf, int s) {
        if constexpr (IS_A) {
            const int ks = s >> 1, gb = (s & 1) * 2;
            accx[gb]     = __builtin_amdgcn_mfma_f32_16x16x32_f16(aX[ks], wf[gb][ks],     accx[gb],     0, 0, 0);
            accx[gb + 1] = __builtin_amdgcn_mfma_f32_16x16x32_f16(aX[ks], wf[gb + 1][ks], accx[gb + 1], 0, 0, 0);
        } else {
#pragma unroll
            for (int g = 0; g < 4; g++)
                accx[g] = __builtin_amdgcn_mfma_f32_16x16x32_f16(rH[buf][s], wf[g][s], accx[g], 0, 0, 0);
        }
    };
    auto xWrite = [&](int kn) {      // C row r16=kc*4+rr -> (s=r16>>2, brow=r16&3)
        float* xzw = &smxz[(kn & 1) * 8192];
#pragma unroll
        for (int rr = 0; rr < 4; rr++) {
            f4 v = {accx[0][rr], accx[1][rr], accx[2][rr], accx[3][rr]};
            *(f4*)&xzw[((kc * 4 + rr) * 128 + u0 + m) * 4] = v;
        }
    };

    // preamble: block 0 burst into half 0; block 1 loads in flight
    if constexpr (!IS_A) { waitflag(0); }
    __syncthreads();
    loadA(0, 0);
    accxInit(); cvtA(0);
#pragma unroll
    for (int s = 0; s < 4; s++) xPiece(0, s);
    xWrite(0);
    if constexpr (!IS_A) { waitflag(1); }
    __syncthreads();
    loadA(1, 1);

    const h8 hzero = {};
    h8 ha[4];
#pragma unroll
    for (int ks = 0; ks < 4; ks++) ha[ks] = hzero;
    f4 fzero = (f4){0.f, 0.f, 0.f, 0.f};
    asm volatile("" : "+v"(fzero));
    float cst = 0.0f;

#pragma unroll 4
    for (int t = 0; t < T_STEPS; t++) {
        const int s  = t & 3;
        const int k  = t >> 2;
        const int kn = k + 1;

        if (s == 0) {
            if constexpr (!IS_A) {
                int fi = k + 2; if (fi > NB - 1) fi = NB - 1;
                waitflag(fi);
            }
            if (kn < NB) { accxInit(); cvtA(kn & 1); }
        }
        if (s == 1 && k + 2 < NB) loadA(k + 2, (k + 2) & 1);
        if (kn < NB) xPiece(kn & 1, s);
        if (s == 3 && kn < NB) xWrite(kn);

        // xz gate-vector (all 64 lanes are real now)
        const f4 xzv = *(const f4*)&smxz[(k & 1) * 8192
                                         + ((s * 4 + erow) * 128 + u0 + m) * 4];

        // A-frags for h@U: brow r at A-row 4r (lanes m=0,4,8,12)
        if ((m & 3) == 0) {
            const _Float16* hb = &smh[(t & 1) * 4 * PH + (m >> 2) * PH];
#pragma unroll
            for (int ks = 0; ks < 4; ks++)
                ha[ks] = *(const h8*)&hb[ks * 32 + kc * 8];
        }
        f4 acc[4];
#pragma unroll
        for (int g = 0; g < 4; g++)
            acc[g] = __builtin_amdgcn_mfma_f32_16x16x32_f16(ha[0], uf[g][0], fzero, 0, 0, 0);
#pragma unroll
        for (int ks = 1; ks < 4; ks++)
#pragma unroll
            for (int g = 0; g < 4; g++)
                acc[g] = __builtin_amdgcn_mfma_f32_16x16x32_f16(ha[ks], uf[g][ks], acc[g], 0, 0, 0);

        // epilogue: all 64 lanes, one (brow, unit) chain each
        {
            float gi = sigm2(acc[0][0] + xzv[0]);
            float gf = sigm2(acc[1][0] + xzv[1]);
            float gg = tanh2(acc[2][0] + xzv[2]);
            float go = sigm2(acc[3][0] + xzv[3]);
            cst = gf * cst + gi * gg;
            float hv = go * tanh2(cst * TWOLOG2E);
            _Float16 h16 = (_Float16)hv;
            smh[((t & 1) ^ 1) * 4 * PH + erow * PH + u0 + m] = h16;
            if constexpr (IS_A)
                hs[((size_t)t * BATCH + b0 + erow) * NU + u0 + m] = h16;
        }

        if (IS_A && s == 3) {
            __syncthreads();           // drains all waves' hs stores (vmcnt)
            if (tid == 0)
                __hip_atomic_store(&flags[wg * NB + k], FLAGV + k,
                                   __ATOMIC_RELEASE, __HIP_MEMORY_SCOPE_AGENT);
        } else {
            WG_BARRIER();
        }
    }

    if constexpr (!IS_A) {
        // h(T) in buffer 0 (t=255 wrote (1^1)=0). Dense on wave 0.
        if (wv == 0) {
            const int rw = lane >> 4, u = lane & 15;
            const _Float16* hb = &smh[rw * PH];
            float sacc = 0.0f;
#pragma unroll
            for (int j = 0; j < 8; j++)
                sacc += (float)hb[u + 16 * j] * Wd[u + 16 * j];
            sacc += __shfl_xor(sacc, 1);
            sacc += __shfl_xor(sacc, 2);
            sacc += __shfl_xor(sacc, 4);
            sacc += __shfl_xor(sacc, 8);
            if (u == 0) dout[b0 + rw] = fmaxf(sacc + bd[0], 0.0f);
        }
    }
}

__attribute__((amdgpu_waves_per_eu(2, 2)))
__global__ __launch_bounds__(512) void lstm_fused(
    const float* __restrict__ x,
    const _Float16* __restrict__ Wp1, const _Float16* __restrict__ Up1,
    const float* __restrict__ bp1,
    const _Float16* __restrict__ Wp2, const _Float16* __restrict__ Up2,
    const float* __restrict__ bp2,
    _Float16* __restrict__ hs, const float* __restrict__ Wd,
    const float* __restrict__ bd, float* __restrict__ dout, int* flags) {
    __shared__ __align__(16) _Float16 smh[8 * 136];
    __shared__ __align__(16) float    smxz[2 * 8192];
    const int bi = blockIdx.x;
    if (bi < 128)
        lstm_body<true>(smh, smxz, x, nullptr, Wp1, Up1, bp1, hs,
                        nullptr, nullptr, nullptr, flags, bi);
    else
        lstm_body<false>(smh, smxz, nullptr, hs, Wp2, Up2, bp2, nullptr,
                         Wd, bd, dout, flags, bi - 128);
}

extern "C" void kernel_launch(void* const* d_in, const int* in_sizes, int n_in,
                              void* d_out, int out_size, void* d_ws, size_t ws_size,
                              hipStream_t stream) {
    const float* x  = (const float*)d_in[0];
    const float* W1 = (const float*)d_in[1];
    const float* U1 = (const float*)d_in[2];
    const float* b1 = (const float*)d_in[3];
    const float* W2 = (const float*)d_in[4];
    const float* U2 = (const float*)d_in[5];
    const float* b2 = (const float*)d_in[6];
    const float* Wd = (const float*)d_in[7];
    const float* bd = (const float*)d_in[8];
    float* out = (float*)d_out;

    const size_t HS   = 33554432;              // hs fp16 [256][512][128]
    const size_t oWp1 = HS;
    const size_t oUp1 = oWp1 + 65536;
    const size_t oWp2 = oUp1 + 131072;
    const size_t oUp2 = oWp2 + 131072;
    const size_t oBp1 = oUp2 + 131072;
    const size_t oBp2 = oBp1 + 2048;
    const size_t oFlg = oBp2 + 2048;
    const size_t need = oFlg + 128 * NB * sizeof(int);   // +32 KB flags
    if (ws_size < need) return;

    char* ws = (char*)d_ws;
    _Float16* hs  = (_Float16*)ws;
    _Float16* Wp1 = (_Float16*)(ws + oWp1);
    _Float16* Up1 = (_Float16*)(ws + oUp1);
    _Float16* Wp2 = (_Float16*)(ws + oWp2);
    _Float16* Up2 = (_Float16*)(ws + oUp2);
    float*    bp1 = (float*)(ws + oBp1);
    float*    bp2 = (float*)(ws + oBp2);
    int*      flg = (int*)(ws + oFlg);

    prep_weights<<<900, 256, 0, stream>>>(W1, U1, b1, W2, U2, b2,
                                          Wp1, Up1, Wp2, Up2, bp1, bp2);
    lstm_fused<<<256, 512, 0, stream>>>(x, Wp1, Up1, bp1, Wp2, Up2, bp2,
                                        hs, Wd, bd, out, flg);
}

// Round 10
// 522.043 us; speedup vs baseline: 8.0269x; 8.0269x over previous
//
#include <hip/hip_runtime.h>

// SimpleLSTM: 2-layer LSTM (B=512,T=256,F=64,U=128) + Dense(1,relu).
// R10: IN-WORKGROUP layer fusion (R9's cross-XCD flags caused buffer_inv/wbl2
// L2-annihilation storms -> 12x regression; all sync now intra-WG).
// Each WG owns 2 batch rows and runs BOTH layers, layer2 lagging 8 steps.
// h1 history in an LDS ring (16 slots) => W2@h1 stays time-batched M=16 at
// 8-step boundaries, exactly like x@W1. Per step both h@U chains share one
// A-frag (h1 rows at A-rows 0/4, h2 rows at 8/12), so the epilogue fills all
// 64 lanes: L1 chains on lanes 0-31, L2 on lanes 32-63. hs never materializes
// in global. 256 WGs x 512 thr; ~70 MFMA/SIMD/step ~= 1360 cyc floor.

#define T_STEPS 256
#define BATCH   512
#define NU      128
#define FDIM    64
#define PH      136   // LDS row pitch (halfs)

typedef _Float16 h8 __attribute__((ext_vector_type(8)));
typedef float    f4 __attribute__((ext_vector_type(4)));

#define LOG2E    1.4426950408889634f
#define TWOLOG2E 2.8853900817779268f

// LDS-only barrier: no global stores in the step loop, loads wait at use.
#define WG_BARRIER() asm volatile("s_waitcnt lgkmcnt(0)\n\ts_barrier" ::: "memory")

#if __has_builtin(__builtin_amdgcn_exp2f)
#define EXP2F(x) __builtin_amdgcn_exp2f(x)
#else
#define EXP2F(x) exp2f(x)
#endif
#if __has_builtin(__builtin_amdgcn_rcpf)
#define RCPF(x) __builtin_amdgcn_rcpf(x)
#else
#define RCPF(x) (1.0f / (x))
#endif

__device__ __forceinline__ float sigm2(float s) {   // s = -z*log2e
    return RCPF(1.0f + EXP2F(s));
}
__device__ __forceinline__ float tanh2(float t) {   // t = 2*z*log2e
    return 1.0f - 2.0f * RCPF(1.0f + EXP2F(t));
}

// ---- weight prep: col-major [col][k], fp16, gate-folded log2e signs ----
// gates 0=i 1=f 2=g 3=o; i/f/o scaled -log2e (sigm2), g scaled +2log2e.
__global__ void prep_weights(const float* __restrict__ W1, const float* __restrict__ U1,
                             const float* __restrict__ b1, const float* __restrict__ W2,
                             const float* __restrict__ U2, const float* __restrict__ b2,
                             _Float16* __restrict__ Wp1, _Float16* __restrict__ Up1,
                             _Float16* __restrict__ Wp2, _Float16* __restrict__ Up2,
                             float* __restrict__ bp1, float* __restrict__ bp2) {
    int i = blockIdx.x * 256 + threadIdx.x;
    if (i < 32768) {                        // Wp1 [512][64] <- W1 [64][512]
        int col = i >> 6, k = i & 63;
        float sc = ((col >> 7) == 2) ? TWOLOG2E : -LOG2E;
        Wp1[i] = (_Float16)(W1[k * 512 + col] * sc);
    } else if (i < 98304) {                 // Up1 [512][128] <- U1
        int j = i - 32768; int col = j >> 7, k = j & 127;
        float sc = ((col >> 7) == 2) ? TWOLOG2E : -LOG2E;
        Up1[j] = (_Float16)(U1[k * 512 + col] * sc);
    } else if (i < 163840) {                // Wp2 [512][128] <- W2
        int j = i - 98304; int col = j >> 7, k = j & 127;
        float sc = ((col >> 7) == 2) ? TWOLOG2E : -LOG2E;
        Wp2[j] = (_Float16)(W2[k * 512 + col] * sc);
    } else if (i < 229376) {                // Up2 [512][128] <- U2
        int j = i - 163840; int col = j >> 7, k = j & 127;
        float sc = ((col >> 7) == 2) ? TWOLOG2E : -LOG2E;
        Up2[j] = (_Float16)(U2[k * 512 + col] * sc);
    } else if (i < 230400) {
        int j = i - 229376;
        if (j < 512) {
            float sc = ((j >> 7) == 2) ? TWOLOG2E : -LOG2E;
            bp1[j] = b1[j] * sc;
        } else {
            int col = j - 512;
            float sc = ((col >> 7) == 2) ? TWOLOG2E : -LOG2E;
            bp2[col] = b2[col] * sc;
        }
    }
}

__attribute__((amdgpu_waves_per_eu(2, 2)))
__global__ __launch_bounds__(512) void lstm_fused(
    const float* __restrict__ x,
    const _Float16* __restrict__ Wp1, const _Float16* __restrict__ Up1,
    const float* __restrict__ bp1,
    const _Float16* __restrict__ Wp2, const _Float16* __restrict__ Up2,
    const float* __restrict__ bp2,
    const float* __restrict__ Wd, const float* __restrict__ bd,
    float* __restrict__ dout) {
    // LDS: h1 ring [16 slot][2 row][PH] + h2 dbuf [2 par][2 row][PH]
    __shared__ __align__(16) _Float16 smh[(32 + 4) * PH];
    // xz1|xz2: [half][r16=s*2+row][u:128] f4 each (32 KB per half)
    __shared__ __align__(16) float smxz[32768];
    _Float16* h1r = smh;
    _Float16* h2r = smh + 32 * PH;
    float* xz1 = smxz;
    float* xz2 = smxz + 16384;

    const int tid  = threadIdx.x;
    const int lane = tid & 63;
    const int wv   = tid >> 6;           // each wave owns 16 units x 4 gates
    const int m    = lane & 15;
    const int kc   = lane >> 4;
    const int u0   = wv * 16;
    const int b0   = blockIdx.x * 2;
    const int erow = (lane >> 4) & 1;    // epilogue batch row within layer

    for (int i = tid; i < 36 * PH; i += 512) smh[i] = (_Float16)0.0f;
    for (int i = tid; i < 32768; i += 512) smxz[i] = 0.0f;

    // hot B-frags (resident): B[k=kc*8+j][n=u0+m]
    h8 uf1[4][4], uf2[4][4];
#pragma unroll
    for (int g = 0; g < 4; g++)
#pragma unroll
        for (int ks = 0; ks < 4; ks++) {
            uf1[g][ks] = *(const h8*)&Up1[(g * 128 + u0 + m) * 128 + ks * 32 + kc * 8];
            uf2[g][ks] = *(const h8*)&Up2[(g * 128 + u0 + m) * 128 + ks * 32 + kc * 8];
        }
    float b1v[4], b2v[4];
#pragma unroll
    for (int g = 0; g < 4; g++) {
        b1v[g] = bp1[g * 128 + u0 + m];
        b2v[g] = bp2[g * 128 + u0 + m];
    }

    __syncthreads();

    const h8 hz = {};
    h8 ha[4];
#pragma unroll
    for (int ks = 0; ks < 4; ks++) ha[ks] = hz;
    f4 fz = (f4){0.f, 0.f, 0.f, 0.f};
    asm volatile("" : "+v"(fz));
    float cst = 0.0f;                    // lanes<32: c1 ; lanes>=32: c2

#pragma unroll 8
    for (int t = 0; t < T_STEPS + 8; t++) {
        const int s = t & 7;
        const int b = t >> 3;

        if (s == 0) {
            if (b < 32) {                // xz1 block b (x @ W1, M=16: 8 steps x 2 rows)
                const int tt = b * 8 + (m >> 1), bb = b0 + (m & 1);
                const float* xp = &x[((size_t)bb * T_STEPS + tt) * FDIM];
                f4 x0 = *(const f4*)&xp[kc * 8];
                f4 x1 = *(const f4*)&xp[kc * 8 + 4];
                f4 x2 = *(const f4*)&xp[32 + kc * 8];
                f4 x3 = *(const f4*)&xp[32 + kc * 8 + 4];
                h8 a0, a1;
#pragma unroll
                for (int j = 0; j < 4; j++) {
                    a0[j] = (_Float16)x0[j]; a0[4 + j] = (_Float16)x1[j];
                    a1[j] = (_Float16)x2[j]; a1[4 + j] = (_Float16)x3[j];
                }
                f4 ax[4];
#pragma unroll
                for (int g = 0; g < 4; g++) {
                    ax[g] = (f4){b1v[g], b1v[g], b1v[g], b1v[g]};
                    h8 w0 = *(const h8*)&Wp1[(g * 128 + u0 + m) * 64 + kc * 8];
                    h8 w1 = *(const h8*)&Wp1[(g * 128 + u0 + m) * 64 + 32 + kc * 8];
                    ax[g] = __builtin_amdgcn_mfma_f32_16x16x32_f16(a0, w0, ax[g], 0, 0, 0);
                    ax[g] = __builtin_amdgcn_mfma_f32_16x16x32_f16(a1, w1, ax[g], 0, 0, 0);
                }
                float* dstz = &xz1[(b & 1) * 8192];
#pragma unroll
                for (int rr = 0; rr < 4; rr++) {
                    f4 v = {ax[0][rr], ax[1][rr], ax[2][rr], ax[3][rr]};
                    *(f4*)&dstz[((kc * 4 + rr) * 128 + u0 + m) * 4] = v;
                }
            }
            if (b >= 1 && b < 33) {      // xz2 block b2=b-1 (h1-ring @ W2, M=16)
                const int b2 = b - 1, hh = b2 & 1;
                const _Float16* hp = &h1r[((hh * 8 + (m >> 1)) * 2 + (m & 1)) * PH];
                h8 a[4];
#pragma unroll
                for (int ks = 0; ks < 4; ks++)
                    a[ks] = *(const h8*)&hp[ks * 32 + kc * 8];
                f4 ax[4];
#pragma unroll
                for (int g = 0; g < 4; g++)
                    ax[g] = (f4){b2v[g], b2v[g], b2v[g], b2v[g]};
#pragma unroll
                for (int ks = 0; ks < 4; ks++)
#pragma unroll
                    for (int g = 0; g < 4; g++) {
                        h8 w = *(const h8*)&Wp2[(g * 128 + u0 + m) * 128 + ks * 32 + kc * 8];
                        ax[g] = __builtin_amdgcn_mfma_f32_16x16x32_f16(a[ks], w, ax[g], 0, 0, 0);
                    }
                float* dstz = &xz2[hh * 8192];
#pragma unroll
                for (int rr = 0; rr < 4; rr++) {
                    f4 v = {ax[0][rr], ax[1][rr], ax[2][rr], ax[3][rr]};
                    *(f4*)&dstz[((kc * 4 + rr) * 128 + u0 + m) * 4] = v;
                }
            }
            WG_BARRIER();                // xz halves visible
        }

        // shared A-frag: h1(t-1) rows at A-rows 0,4 ; h2(t-1) rows at 8,12
        if ((m & 3) == 0) {
            const _Float16* src = (m < 8)
                ? &h1r[(((t - 1) & 15) * 2 + (m >> 2)) * PH]
                : &h2r[((t & 1) * 2 + ((m >> 2) - 2)) * PH];
#pragma unroll
            for (int ks = 0; ks < 4; ks++)
                ha[ks] = *(const h8*)&src[ks * 32 + kc * 8];
        }

        f4 ac1[4], ac2[4];
#pragma unroll
        for (int g = 0; g < 4; g++) {
            ac1[g] = __builtin_amdgcn_mfma_f32_16x16x32_f16(ha[0], uf1[g][0], fz, 0, 0, 0);
            ac2[g] = __builtin_amdgcn_mfma_f32_16x16x32_f16(ha[0], uf2[g][0], fz, 0, 0, 0);
        }
#pragma unroll
        for (int ks = 1; ks < 4; ks++)
#pragma unroll
            for (int g = 0; g < 4; g++) {
                ac1[g] = __builtin_amdgcn_mfma_f32_16x16x32_f16(ha[ks], uf1[g][ks], ac1[g], 0, 0, 0);
                ac2[g] = __builtin_amdgcn_mfma_f32_16x16x32_f16(ha[ks], uf2[g][ks], ac2[g], 0, 0, 0);
            }

        // epilogue: all 64 lanes. lanes<32 = L1 step t ; lanes>=32 = L2 step t-8.
        {
            const bool l1 = (lane < 32);
            const float* xb = l1 ? &xz1[(b & 1) * 8192]
                                 : &xz2[((b - 1) & 1) * 8192];
            f4 xzv = *(const f4*)&xb[((s * 2 + erow) * 128 + u0 + m) * 4];
            float z0 = (l1 ? ac1[0][0] : ac2[0][0]) + xzv[0];
            float z1 = (l1 ? ac1[1][0] : ac2[1][0]) + xzv[1];
            float z2 = (l1 ? ac1[2][0] : ac2[2][0]) + xzv[2];
            float z3 = (l1 ? ac1[3][0] : ac2[3][0]) + xzv[3];
            float gi = sigm2(z0), gf = sigm2(z1);
            float gg = tanh2(z2), go = sigm2(z3);
            cst = gf * cst + gi * gg;
            float hv = go * tanh2(cst * TWOLOG2E);
            _Float16 h16 = (_Float16)hv;
            _Float16* dst = l1
                ? &h1r[((t & 15) * 2 + erow) * PH + u0 + m]
                : &h2r[(((t & 1) ^ 1) * 2 + erow) * PH + u0 + m];
            *dst = h16;
        }
        WG_BARRIER();
    }

    // dense: h2 final written at t=263 -> h2r parity 0
    if (wv == 0 && lane < 32) {
        const int rw = lane >> 4, u = lane & 15;
        const _Float16* hb = &h2r[rw * PH];
        float sa = 0.0f;
#pragma unroll
        for (int j = 0; j < 8; j++)
            sa += (float)hb[u + 16 * j] * Wd[u + 16 * j];
        sa += __shfl_xor(sa, 1);
        sa += __shfl_xor(sa, 2);
        sa += __shfl_xor(sa, 4);
        sa += __shfl_xor(sa, 8);
        if (u == 0) dout[b0 + rw] = fmaxf(sa + bd[0], 0.0f);
    }
}

extern "C" void kernel_launch(void* const* d_in, const int* in_sizes, int n_in,
                              void* d_out, int out_size, void* d_ws, size_t ws_size,
                              hipStream_t stream) {
    const float* x  = (const float*)d_in[0];
    const float* W1 = (const float*)d_in[1];
    const float* U1 = (const float*)d_in[2];
    const float* b1 = (const float*)d_in[3];
    const float* W2 = (const float*)d_in[4];
    const float* U2 = (const float*)d_in[5];
    const float* b2 = (const float*)d_in[6];
    const float* Wd = (const float*)d_in[7];
    const float* bd = (const float*)d_in[8];
    float* out = (float*)d_out;

    const size_t oWp1 = 0;                 // 65536 B
    const size_t oUp1 = 65536;             // 131072 B
    const size_t oWp2 = 196608;            // 131072 B
    const size_t oUp2 = 327680;            // 131072 B
    const size_t oBp1 = 458752;            // 2048 B
    const size_t oBp2 = 460800;            // 2048 B
    const size_t need = 462848;
    if (ws_size < need) return;

    char* ws = (char*)d_ws;
    _Float16* Wp1 = (_Float16*)(ws + oWp1);
    _Float16* Up1 = (_Float16*)(ws + oUp1);
    _Float16* Wp2 = (_Float16*)(ws + oWp2);
    _Float16* Up2 = (_Float16*)(ws + oUp2);
    float*    bp1 = (float*)(ws + oBp1);
    float*    bp2 = (float*)(ws + oBp2);

    prep_weights<<<900, 256, 0, stream>>>(W1, U1, b1, W2, U2, b2,
                                          Wp1, Up1, Wp2, Up2, bp1, bp2);
    lstm_fused<<<256, 512, 0, stream>>>(x, Wp1, Up1, bp1, Wp2, Up2, bp2,
                                        Wd, bd, out);
}